// Round 4
// baseline (958.175 us; speedup 1.0000x reference)
//
#include <hip/hip_runtime.h>
#include <hip/hip_bf16.h>
#include <math.h>

#define TILE 128
#define BK 64

using short8 = __attribute__((ext_vector_type(8))) short;
using f32x4  = __attribute__((ext_vector_type(4))) float;
typedef __hip_bfloat16 bf16;

constexpr int BB = 8, SEQ = 2048, C = 1024, H3 = 3072, DH = 512, MH = 2048;
constexpr int MR = BB * SEQ;  // 16384 token rows

enum {
  F_TRANSB = 1,   // B given as [N,K] row-major
  F_GELU   = 2,
  F_RES    = 4,
  F_OUTBF16= 8,
  F_BIAS   = 16,
  F_SCALE  = 32,
  F_RESF32 = 64
};

struct ZOffs { long long a[16]; long long b[16]; long long c[16]; };

__device__ __forceinline__ float bf2f(bf16 h) { return __bfloat162float(h); }

// async global->LDS, 16B per lane; LDS dest must be wave-uniform base + lane*16
__device__ __forceinline__ void gload16(const void* g, void* l) {
  __builtin_amdgcn_global_load_lds(
      (const __attribute__((address_space(1))) unsigned int*)g,
      (__attribute__((address_space(3))) unsigned int*)l, 16, 0, 0);
}

// ---------- GEMM: D[M,N] = epilogue(A[M,K]@B + bias (+res)); A,B bf16 ----------
// block 256 = 4 waves; tile 128x128, BK=64; wave -> 64x64 (4x4 of 16x16x32 MFMA)
// m97 staging (global_load_lds width-16, unpadded LDS) with 2x K-unroll per barrier.
template<int FLAGS>
__global__ __launch_bounds__(256) void gemm_k(
    const bf16* __restrict__ A,
    const bf16* __restrict__ B,
    void* __restrict__ Dst,
    const float* __restrict__ bias,
    const void* __restrict__ res,
    int K, int lda, int ldb, int ldc,
    float scale, ZOffs zo)
{
  __shared__ __align__(16) unsigned short As[TILE * BK];   // [row][k] 16 KB
  __shared__ __align__(16) unsigned short Bs[TILE * BK];   // [n][k]   16 KB
  const int tid = threadIdx.x;
  const int z = blockIdx.z;
  const int m0 = blockIdx.y * TILE, n0 = blockIdx.x * TILE;
  const bf16* Ab = A + zo.a[z];
  const bf16* Bb = B + zo.b[z];
  const long long coff = zo.c[z];
  const int wave = tid >> 6, lane = tid & 63;
  const int wm = (wave & 1) << 6, wn = (wave >> 1) << 6;
  const int lr = lane & 15, lq = lane >> 4;
  // staging map: chunk c in [0,1024): row = c>>3, col8 = (c&7)*8; c = tid + i*256
  const int sr = tid >> 3, sc = (tid & 7) << 3;

  f32x4 acc[4][4] = {};

  for (int k0 = 0; k0 < K; k0 += BK) {
    #pragma unroll
    for (int i = 0; i < 4; i++)
      gload16(Ab + (size_t)(m0 + sr + i * 32) * lda + k0 + sc,
              &As[(tid + i * 256) * 8]);
    if (FLAGS & F_TRANSB) {
      #pragma unroll
      for (int i = 0; i < 4; i++)
        gload16(Bb + (size_t)(n0 + sr + i * 32) * ldb + k0 + sc,
                &Bs[(tid + i * 256) * 8]);
    } else {
      // B is [K,N] row-major: transpose-scatter into Bs[n][k] (fallback path)
      #pragma unroll
      for (int i = 0; i < 4; i++) {
        int c = tid + i * 256;
        int kk = c >> 4, nn = (c & 15) << 3;
        unsigned short tmp[8];
        *(uint4*)tmp = *(const uint4*)(Bb + (size_t)(k0 + kk) * ldb + n0 + nn);
        #pragma unroll
        for (int j = 0; j < 8; j++) Bs[(nn + j) * BK + kk] = tmp[j];
      }
    }
    __syncthreads();
    #pragma unroll
    for (int ks = 0; ks < 2; ks++) {
      short8 af[4], bfr[4];
      #pragma unroll
      for (int mi = 0; mi < 4; mi++)
        af[mi] = *(const short8*)&As[(wm + mi * 16 + lr) * BK + ks * 32 + lq * 8];
      #pragma unroll
      for (int ni = 0; ni < 4; ni++)
        bfr[ni] = *(const short8*)&Bs[(wn + ni * 16 + lr) * BK + ks * 32 + lq * 8];
      #pragma unroll
      for (int mi = 0; mi < 4; mi++)
        #pragma unroll
        for (int ni = 0; ni < 4; ni++)
          acc[mi][ni] = __builtin_amdgcn_mfma_f32_16x16x32_bf16(
              af[mi], bfr[ni], acc[mi][ni], 0, 0, 0);
    }
    __syncthreads();
  }

  // epilogue: C/D layout col=lane&15, row=quad*4+reg
  #pragma unroll
  for (int mi = 0; mi < 4; mi++) {
    #pragma unroll
    for (int ni = 0; ni < 4; ni++) {
      int col = n0 + wn + ni * 16 + lr;
      float bv = (FLAGS & F_BIAS) ? bias[col] : 0.0f;
      #pragma unroll
      for (int r = 0; r < 4; r++) {
        int row = m0 + wm + mi * 16 + lq * 4 + r;
        float v = acc[mi][ni][r];
        if (FLAGS & F_SCALE) v *= scale;
        v += bv;
        if (FLAGS & F_GELU) v = 0.5f * v * (1.0f + erff(v * 0.70710678118654752f));
        if (FLAGS & F_RES) {
          size_t ridx = (size_t)row * ldc + col;
          v += (FLAGS & F_RESF32) ? ((const float*)res)[ridx]
                                  : bf2f(((const bf16*)res)[ridx]);
        }
        size_t idx = (size_t)coff + (size_t)row * ldc + col;
        if (FLAGS & F_OUTBF16) ((bf16*)Dst)[idx] = __float2bfloat16(v);
        else                   ((float*)Dst)[idx] = v;
      }
    }
  }
}

// ---------- weight transpose+convert: src fp32 [K,N] -> dst bf16 [N,K] ----------
__global__ __launch_bounds__(256) void tconv_kernel(
    const float* __restrict__ src, bf16* __restrict__ dst, int K, int N)
{
  __shared__ float t[32][33];
  int n0 = blockIdx.x * 32, k0 = blockIdx.y * 32;
  int c = threadIdx.x & 31, r = threadIdx.x >> 5;
  #pragma unroll
  for (int i = 0; i < 4; i++)
    t[r + i * 8][c] = src[(size_t)(k0 + r + i * 8) * N + n0 + c];
  __syncthreads();
  #pragma unroll
  for (int i = 0; i < 4; i++)
    dst[(size_t)(n0 + r + i * 8) * K + k0 + c] = __float2bfloat16(t[c][r + i * 8]);
}

// ---------- V transpose: qkv V-slice [n][d] -> Vt[bh][d][n] (bf16) ----------
__global__ __launch_bounds__(256) void vtrans_kernel(
    const bf16* __restrict__ qkv, bf16* __restrict__ vt)
{
  __shared__ unsigned short t[32][33];
  int bh = blockIdx.z, b = bh >> 1, h = bh & 1;
  int n0 = blockIdx.x * 32, d0 = blockIdx.y * 32;
  int c = threadIdx.x & 31, r = threadIdx.x >> 5;
  const bf16* src = qkv + (size_t)b * SEQ * H3 + 2 * C + (size_t)h * DH;
  #pragma unroll
  for (int i = 0; i < 4; i++)
    t[r + i * 8][c] = *(const unsigned short*)&src[(size_t)(n0 + r + i * 8) * H3 + d0 + c];
  __syncthreads();
  bf16* dst = vt + ((size_t)bh * DH + d0) * SEQ + n0;
  #pragma unroll
  for (int i = 0; i < 4; i++)
    *(unsigned short*)&dst[(size_t)(r + i * 8) * SEQ + c] = t[c][r + i * 8];
}

// ---------- LayerNorm over C=1024, one block per row ----------
__device__ __forceinline__ float toF(float f) { return f; }
__device__ __forceinline__ float toF(bf16 h) { return __bfloat162float(h); }

template<typename T>
__global__ __launch_bounds__(256) void ln_kernel(
    const T* __restrict__ x,
    const float* __restrict__ w,
    const float* __restrict__ b,
    bf16* __restrict__ out)
{
  __shared__ float sm[4], sm2[4];
  int row = blockIdx.x, tid = threadIdx.x;
  const T* xr = x + (size_t)row * 1024;
  float v[4], s = 0.f, sq = 0.f;
  #pragma unroll
  for (int i = 0; i < 4; i++) {
    v[i] = toF(xr[tid + i * 256]);
    s += v[i]; sq += v[i] * v[i];
  }
  #pragma unroll
  for (int o = 32; o > 0; o >>= 1) {
    s  += __shfl_down(s, o, 64);
    sq += __shfl_down(sq, o, 64);
  }
  int wv = tid >> 6, ln = tid & 63;
  if (ln == 0) { sm[wv] = s; sm2[wv] = sq; }
  __syncthreads();
  s  = sm[0] + sm[1] + sm[2] + sm[3];
  sq = sm2[0] + sm2[1] + sm2[2] + sm2[3];
  float mean = s * (1.0f / 1024.0f);
  float var  = sq * (1.0f / 1024.0f) - mean * mean;
  float rs = rsqrtf(var + 1e-5f);
  #pragma unroll
  for (int i = 0; i < 4; i++) {
    int c = tid + i * 256;
    float o = (v[i] - mean) * rs * w[c] + b[c];
    out[(size_t)row * 1024 + c] = __float2bfloat16(o);
  }
}

// ---------- row softmax over 2048, IN-PLACE (bf16) ----------
__global__ __launch_bounds__(256) void softmax_kernel(
    bf16* __restrict__ sc)
{
  __shared__ float sm[4];
  int tid = threadIdx.x;
  size_t base = ((size_t)blockIdx.y * 2048 + blockIdx.x) * 2048;
  float v[8], m = -1e30f;
  #pragma unroll
  for (int i = 0; i < 8; i++) { v[i] = bf2f(sc[base + tid + i * 256]); m = fmaxf(m, v[i]); }
  #pragma unroll
  for (int o = 32; o > 0; o >>= 1) m = fmaxf(m, __shfl_down(m, o, 64));
  int wv = tid >> 6, ln = tid & 63;
  if (ln == 0) sm[wv] = m;
  __syncthreads();
  m = fmaxf(fmaxf(sm[0], sm[1]), fmaxf(sm[2], sm[3]));
  __syncthreads();
  float s = 0.f;
  #pragma unroll
  for (int i = 0; i < 8; i++) { v[i] = __expf(v[i] - m); s += v[i]; }
  #pragma unroll
  for (int o = 32; o > 0; o >>= 1) s += __shfl_down(s, o, 64);
  if (ln == 0) sm[wv] = s;
  __syncthreads();
  s = sm[0] + sm[1] + sm[2] + sm[3];
  float inv = 1.0f / s;
  #pragma unroll
  for (int i = 0; i < 8; i++)
    sc[base + tid + i * 256] = __float2bfloat16(v[i] * inv);
}

// ---------------- host ----------------
extern "C" void kernel_launch(void* const* d_in, const int* in_sizes, int n_in,
                              void* d_out, int out_size, void* d_ws, size_t ws_size,
                              hipStream_t stream) {
  const float* x      = (const float*)d_in[0];
  const float* ln1_w  = (const float*)d_in[1];
  const float* ln1_b  = (const float*)d_in[2];
  const float* qkv_w  = (const float*)d_in[3];
  const float* qkv_b  = (const float*)d_in[4];
  const float* proj_w = (const float*)d_in[5];
  const float* proj_b = (const float*)d_in[6];
  const float* ln2_w  = (const float*)d_in[7];
  const float* ln2_b  = (const float*)d_in[8];
  const float* mlp_w1 = (const float*)d_in[9];
  const float* mlp_b1 = (const float*)d_in[10];
  const float* mlp_w2 = (const float*)d_in[11];
  const float* mlp_b2 = (const float*)d_in[12];
  float* out = (float*)d_out;

  char* ws = (char*)d_ws;
  const size_t MB = 1ull << 20;
  bf16* qkvT  = (bf16*)ws;
  bf16* projT = qkvT + 3 * 1024 * 1024;
  bf16* w1T   = qkvT + 4 * 1024 * 1024;
  bf16* w2T   = qkvT + 6 * 1024 * 1024;
  bf16* xn    = (bf16*)(ws + 16 * MB);
  bf16* qkvb  = (bf16*)(ws + 48 * MB);
  bf16* h1    = qkvb;
  bf16* Vt    = (bf16*)(ws + 144 * MB);

  int CH; bool useVt, x1f32;
  if      (ws_size >= 304 * MB) { CH = 16; useVt = true;  x1f32 = true;  }
  else if (ws_size >= 240 * MB) { CH = 8;  useVt = true;  x1f32 = true;  }
  else if (ws_size >= 208 * MB) { CH = 4;  useVt = true;  x1f32 = false; }
  else                          { CH = 4;  useVt = false; x1f32 = false; }
  char* R = ws + (useVt ? 176 * MB : 144 * MB);
  bf16*  scores = (bf16*)R;
  float* x1f    = (float*)R;   // overlays scores after attention
  bf16*  x1h    = (bf16*)R;

  ZOffs z0 = {};
  const float scale = 0.04419417382415922f;  // 1/sqrt(512)
  dim3 blk(256);

  // 0. weight transpose+convert
  hipLaunchKernelGGL(tconv_kernel, dim3(H3 / 32, C / 32), blk, 0, stream, qkv_w, qkvT, C, H3);
  hipLaunchKernelGGL(tconv_kernel, dim3(C / 32, C / 32), blk, 0, stream, proj_w, projT, C, C);
  hipLaunchKernelGGL(tconv_kernel, dim3(MH / 32, C / 32), blk, 0, stream, mlp_w1, w1T, C, MH);
  hipLaunchKernelGGL(tconv_kernel, dim3(C / 32, MH / 32), blk, 0, stream, mlp_w2, w2T, MH, C);

  // 1. LN1
  hipLaunchKernelGGL((ln_kernel<float>), dim3(MR), blk, 0, stream, x, ln1_w, ln1_b, xn);

  // 2. QKV = xn @ qkv_w + b -> bf16 [16384,3072]
  hipLaunchKernelGGL((gemm_k<F_TRANSB | F_BIAS | F_OUTBF16>),
                     dim3(H3 / TILE, MR / TILE, 1), blk, 0, stream,
                     xn, qkvT, (void*)qkvb, qkv_b, nullptr, C, C, C, H3, 1.0f, z0);

  // 2b. Vt
  if (useVt)
    hipLaunchKernelGGL(vtrans_kernel, dim3(SEQ / 32, DH / 32, 16), blk, 0, stream, qkvb, Vt);

  // 3. attention in chunks of CH (b,h) pairs
  for (int ch = 0; ch < 16 / CH; ch++) {
    ZOffs zq = {}, zp = {};
    for (int zz = 0; zz < CH; zz++) {
      int bh = ch * CH + zz, b = bh >> 1, hh = bh & 1;
      zq.a[zz] = (long long)b * SEQ * H3 + (long long)hh * DH;          // Q
      zq.b[zz] = (long long)b * SEQ * H3 + C + (long long)hh * DH;      // K
      zq.c[zz] = (long long)zz * SEQ * SEQ;                             // scores
      zp.a[zz] = (long long)zz * SEQ * SEQ;                             // probs
      zp.b[zz] = useVt ? (long long)bh * DH * SEQ                       // Vt slice
                       : (long long)b * SEQ * H3 + 2 * C + (long long)hh * DH;
      zp.c[zz] = (long long)b * SEQ * C + (long long)hh * DH;           // attn_out
    }
    hipLaunchKernelGGL((gemm_k<F_TRANSB | F_SCALE | F_OUTBF16>),
                       dim3(SEQ / TILE, SEQ / TILE, CH), blk, 0, stream,
                       qkvb, qkvb, (void*)scores, nullptr, nullptr, DH, H3, H3, SEQ, scale, zq);
    hipLaunchKernelGGL(softmax_kernel, dim3(SEQ, CH), blk, 0, stream, scores);
    if (useVt)
      hipLaunchKernelGGL((gemm_k<F_TRANSB | F_OUTBF16>),
                         dim3(DH / TILE, SEQ / TILE, CH), blk, 0, stream,
                         scores, Vt, (void*)xn, nullptr, nullptr, SEQ, SEQ, SEQ, C, 1.0f, zp);
    else
      hipLaunchKernelGGL((gemm_k<F_OUTBF16>),
                         dim3(DH / TILE, SEQ / TILE, CH), blk, 0, stream,
                         scores, qkvb, (void*)xn, nullptr, nullptr, SEQ, SEQ, H3, C, 1.0f, zp);
  }

  // 4. x1 = attn_out @ proj_w + b + x ; LN2 -> xn2
  if (x1f32) {
    hipLaunchKernelGGL((gemm_k<F_TRANSB | F_BIAS | F_RES | F_RESF32>),
                       dim3(C / TILE, MR / TILE, 1), blk, 0, stream,
                       xn, projT, (void*)x1f, proj_b, (const void*)x, C, C, C, C, 1.0f, z0);
    hipLaunchKernelGGL((ln_kernel<float>), dim3(MR), blk, 0, stream, x1f, ln2_w, ln2_b, xn);
  } else {
    hipLaunchKernelGGL((gemm_k<F_TRANSB | F_BIAS | F_RES | F_RESF32 | F_OUTBF16>),
                       dim3(C / TILE, MR / TILE, 1), blk, 0, stream,
                       xn, projT, (void*)x1h, proj_b, (const void*)x, C, C, C, C, 1.0f, z0);
    hipLaunchKernelGGL((ln_kernel<bf16>), dim3(MR), blk, 0, stream, x1h, ln2_w, ln2_b, xn);
  }

  // 5. h1 = gelu(xn2 @ w1 + b1) -> bf16 [16384,2048]
  hipLaunchKernelGGL((gemm_k<F_TRANSB | F_BIAS | F_GELU | F_OUTBF16>),
                     dim3(MH / TILE, MR / TILE, 1), blk, 0, stream,
                     xn, w1T, (void*)h1, mlp_b1, nullptr, C, C, C, MH, 1.0f, z0);

  // 6. out = x1 + h1 @ w2 + b2 -> fp32 d_out
  if (x1f32) {
    hipLaunchKernelGGL((gemm_k<F_TRANSB | F_BIAS | F_RES | F_RESF32>),
                       dim3(C / TILE, MR / TILE, 1), blk, 0, stream,
                       h1, w2T, (void*)out, mlp_b2, (const void*)x1f, MH, MH, MH, C, 1.0f, z0);
  } else {
    hipLaunchKernelGGL((gemm_k<F_TRANSB | F_BIAS | F_RES>),
                       dim3(C / TILE, MR / TILE, 1), blk, 0, stream,
                       h1, w2T, (void*)out, mlp_b2, (const void*)x1h, MH, MH, MH, C, 1.0f, z0);
  }
}

// Round 5
// 929.095 us; speedup vs baseline: 1.0313x; 1.0313x over previous
//
#include <hip/hip_runtime.h>
#include <hip/hip_bf16.h>
#include <math.h>

#define TILE 128
#define BK 32

using short8 = __attribute__((ext_vector_type(8))) short;
using f32x4  = __attribute__((ext_vector_type(4))) float;
typedef __hip_bfloat16 bf16;

constexpr int BB = 8, SEQ = 2048, C = 1024, H3 = 3072, DH = 512, MH = 2048;
constexpr int MR = BB * SEQ;  // 16384 token rows

enum {
  F_TRANSB = 1,   // B given as [N,K] row-major
  F_GELU   = 2,
  F_RES    = 4,
  F_OUTBF16= 8,
  F_BIAS   = 16,
  F_SCALE  = 32,
  F_RESF32 = 64
};

struct ZOffs { long long a[16]; long long b[16]; long long c[16]; };

__device__ __forceinline__ float bf2f(bf16 h) { return __bfloat162float(h); }

// async global->LDS, 16B per lane; LDS dest is wave-uniform base + lane*16
__device__ __forceinline__ void gload16(const void* g, void* l) {
  __builtin_amdgcn_global_load_lds(
      (const __attribute__((address_space(1))) unsigned int*)g,
      (__attribute__((address_space(3))) unsigned int*)l, 16, 0, 0);
}

// ---------- GEMM: D[M,N] = epilogue(A[M,K]@B + bias (+res)); A,B bf16 ----------
// block 256 = 4 waves; tile 128x128, BK=32; wave -> 64x64 (4x4 of 16x16x32 MFMA)
// m97 staging (global_load_lds width-16, unpadded LDS [128][32]) with XOR bank
// swizzle: LDS[row][kb'] holds global kb = kb' ^ ((row>>1)&3). Swizzle is applied
// by permuting the SOURCE address per lane (dest stays lane-linear).
template<int FLAGS>
__global__ __launch_bounds__(256) void gemm_k(
    const bf16* __restrict__ A,
    const bf16* __restrict__ B,
    void* __restrict__ Dst,
    const float* __restrict__ bias,
    const void* __restrict__ res,
    int K, int lda, int ldb, int ldc,
    float scale, ZOffs zo)
{
  __shared__ __align__(16) unsigned short As[TILE * BK];   // [row][k] 8 KB
  __shared__ __align__(16) unsigned short Bs[TILE * BK];   // [n][k]   8 KB
  const int tid = threadIdx.x;
  const int z = blockIdx.z;
  const int m0 = blockIdx.y * TILE, n0 = blockIdx.x * TILE;
  const bf16* Ab = A + zo.a[z];
  const bf16* Bb = B + zo.b[z];
  const long long coff = zo.c[z];
  const int wave = tid >> 6, lane = tid & 63;
  const int wm = (wave & 1) << 6, wn = (wave >> 1) << 6;
  const int lr = lane & 15, lq = lane >> 4;

  // staging: chunk c = tid + i*256, c in [0,512): row=c>>2, dest kb'=c&3,
  // source kb = kb' ^ ((row>>1)&3)
  int srow[2], skb[2];
  #pragma unroll
  for (int i = 0; i < 2; i++) {
    int c = tid + (i << 8);
    srow[i] = c >> 2;
    skb[i]  = (c & 3) ^ ((srow[i] >> 1) & 3);
  }
  const bf16* Asrc[2]; const bf16* Bsrc[2] = {nullptr, nullptr};
  #pragma unroll
  for (int i = 0; i < 2; i++)
    Asrc[i] = Ab + (size_t)(m0 + srow[i]) * lda + skb[i] * 8;
  if (FLAGS & F_TRANSB) {
    #pragma unroll
    for (int i = 0; i < 2; i++)
      Bsrc[i] = Bb + (size_t)(n0 + srow[i]) * ldb + skb[i] * 8;
  }

  f32x4 acc[4][4] = {};
  const int swl = (lr >> 1) & 3;          // fragment-read swizzle (uniform over mi/ni)

  for (int k0 = 0; k0 < K; k0 += BK) {
    #pragma unroll
    for (int i = 0; i < 2; i++)
      gload16(Asrc[i] + k0, &As[(tid + (i << 8)) * 8]);
    if (FLAGS & F_TRANSB) {
      #pragma unroll
      for (int i = 0; i < 2; i++)
        gload16(Bsrc[i] + k0, &Bs[(tid + (i << 8)) * 8]);
    } else {
      // B is [K,N] row-major: transpose-scatter into swizzled Bs[n][k]
      #pragma unroll
      for (int i = 0; i < 2; i++) {
        int c = tid + (i << 8);
        int kk = c >> 4, nn = (c & 15) << 3;
        unsigned short tmp[8];
        *(uint4*)tmp = *(const uint4*)(Bb + (size_t)(k0 + kk) * ldb + n0 + nn);
        #pragma unroll
        for (int j = 0; j < 8; j++) {
          int n = nn + j;
          Bs[n * BK + (((kk >> 3) ^ ((n >> 1) & 3)) << 3) + (kk & 7)] = tmp[j];
        }
      }
    }
    __syncthreads();
    short8 af[4], bfr[4];
    #pragma unroll
    for (int mi = 0; mi < 4; mi++)
      af[mi] = *(const short8*)&As[(wm + mi * 16 + lr) * BK + ((lq ^ swl) << 3)];
    #pragma unroll
    for (int ni = 0; ni < 4; ni++)
      bfr[ni] = *(const short8*)&Bs[(wn + ni * 16 + lr) * BK + ((lq ^ swl) << 3)];
    #pragma unroll
    for (int mi = 0; mi < 4; mi++)
      #pragma unroll
      for (int ni = 0; ni < 4; ni++)
        acc[mi][ni] = __builtin_amdgcn_mfma_f32_16x16x32_bf16(
            af[mi], bfr[ni], acc[mi][ni], 0, 0, 0);
    __syncthreads();
  }

  // epilogue: C/D layout col=lane&15, row=quad*4+reg
  #pragma unroll
  for (int mi = 0; mi < 4; mi++) {
    #pragma unroll
    for (int ni = 0; ni < 4; ni++) {
      int col = n0 + wn + ni * 16 + lr;
      float bv = (FLAGS & F_BIAS) ? bias[col] : 0.0f;
      #pragma unroll
      for (int r = 0; r < 4; r++) {
        int row = m0 + wm + mi * 16 + lq * 4 + r;
        float v = acc[mi][ni][r];
        if (FLAGS & F_SCALE) v *= scale;
        v += bv;
        if (FLAGS & F_GELU) v = 0.5f * v * (1.0f + erff(v * 0.70710678118654752f));
        if (FLAGS & F_RES) {
          size_t ridx = (size_t)row * ldc + col;
          v += (FLAGS & F_RESF32) ? ((const float*)res)[ridx]
                                  : bf2f(((const bf16*)res)[ridx]);
        }
        size_t idx = (size_t)coff + (size_t)row * ldc + col;
        if (FLAGS & F_OUTBF16) ((bf16*)Dst)[idx] = __float2bfloat16(v);
        else                   ((float*)Dst)[idx] = v;
      }
    }
  }
}

// ---------- weight transpose+convert: src fp32 [K,N] -> dst bf16 [N,K] ----------
__global__ __launch_bounds__(256) void tconv_kernel(
    const float* __restrict__ src, bf16* __restrict__ dst, int K, int N)
{
  __shared__ float t[32][33];
  int n0 = blockIdx.x * 32, k0 = blockIdx.y * 32;
  int c = threadIdx.x & 31, r = threadIdx.x >> 5;
  #pragma unroll
  for (int i = 0; i < 4; i++)
    t[r + i * 8][c] = src[(size_t)(k0 + r + i * 8) * N + n0 + c];
  __syncthreads();
  #pragma unroll
  for (int i = 0; i < 4; i++)
    dst[(size_t)(n0 + r + i * 8) * K + k0 + c] = __float2bfloat16(t[c][r + i * 8]);
}

// ---------- V transpose: qkv V-slice [n][d] -> Vt[bh][d][n] (bf16) ----------
__global__ __launch_bounds__(256) void vtrans_kernel(
    const bf16* __restrict__ qkv, bf16* __restrict__ vt)
{
  __shared__ unsigned short t[32][33];
  int bh = blockIdx.z, b = bh >> 1, h = bh & 1;
  int n0 = blockIdx.x * 32, d0 = blockIdx.y * 32;
  int c = threadIdx.x & 31, r = threadIdx.x >> 5;
  const bf16* src = qkv + (size_t)b * SEQ * H3 + 2 * C + (size_t)h * DH;
  #pragma unroll
  for (int i = 0; i < 4; i++)
    t[r + i * 8][c] = *(const unsigned short*)&src[(size_t)(n0 + r + i * 8) * H3 + d0 + c];
  __syncthreads();
  bf16* dst = vt + ((size_t)bh * DH + d0) * SEQ + n0;
  #pragma unroll
  for (int i = 0; i < 4; i++)
    *(unsigned short*)&dst[(size_t)(r + i * 8) * SEQ + c] = t[c][r + i * 8];
}

// ---------- LayerNorm over C=1024, one block per row ----------
__device__ __forceinline__ float toF(float f) { return f; }
__device__ __forceinline__ float toF(bf16 h) { return __bfloat162float(h); }

template<typename T>
__global__ __launch_bounds__(256) void ln_kernel(
    const T* __restrict__ x,
    const float* __restrict__ w,
    const float* __restrict__ b,
    bf16* __restrict__ out)
{
  __shared__ float sm[4], sm2[4];
  int row = blockIdx.x, tid = threadIdx.x;
  const T* xr = x + (size_t)row * 1024;
  float v[4], s = 0.f, sq = 0.f;
  #pragma unroll
  for (int i = 0; i < 4; i++) {
    v[i] = toF(xr[tid + i * 256]);
    s += v[i]; sq += v[i] * v[i];
  }
  #pragma unroll
  for (int o = 32; o > 0; o >>= 1) {
    s  += __shfl_down(s, o, 64);
    sq += __shfl_down(sq, o, 64);
  }
  int wv = tid >> 6, ln = tid & 63;
  if (ln == 0) { sm[wv] = s; sm2[wv] = sq; }
  __syncthreads();
  s  = sm[0] + sm[1] + sm[2] + sm[3];
  sq = sm2[0] + sm2[1] + sm2[2] + sm2[3];
  float mean = s * (1.0f / 1024.0f);
  float var  = sq * (1.0f / 1024.0f) - mean * mean;
  float rs = rsqrtf(var + 1e-5f);
  #pragma unroll
  for (int i = 0; i < 4; i++) {
    int c = tid + i * 256;
    float o = (v[i] - mean) * rs * w[c] + b[c];
    out[(size_t)row * 1024 + c] = __float2bfloat16(o);
  }
}

// ---------- row softmax over 2048, IN-PLACE (bf16) ----------
__global__ __launch_bounds__(256) void softmax_kernel(
    bf16* __restrict__ sc)
{
  __shared__ float sm[4];
  int tid = threadIdx.x;
  size_t base = ((size_t)blockIdx.y * 2048 + blockIdx.x) * 2048;
  float v[8], m = -1e30f;
  #pragma unroll
  for (int i = 0; i < 8; i++) { v[i] = bf2f(sc[base + tid + i * 256]); m = fmaxf(m, v[i]); }
  #pragma unroll
  for (int o = 32; o > 0; o >>= 1) m = fmaxf(m, __shfl_down(m, o, 64));
  int wv = tid >> 6, ln = tid & 63;
  if (ln == 0) sm[wv] = m;
  __syncthreads();
  m = fmaxf(fmaxf(sm[0], sm[1]), fmaxf(sm[2], sm[3]));
  __syncthreads();
  float s = 0.f;
  #pragma unroll
  for (int i = 0; i < 8; i++) { v[i] = __expf(v[i] - m); s += v[i]; }
  #pragma unroll
  for (int o = 32; o > 0; o >>= 1) s += __shfl_down(s, o, 64);
  if (ln == 0) sm[wv] = s;
  __syncthreads();
  s = sm[0] + sm[1] + sm[2] + sm[3];
  float inv = 1.0f / s;
  #pragma unroll
  for (int i = 0; i < 8; i++)
    sc[base + tid + i * 256] = __float2bfloat16(v[i] * inv);
}

// ---------------- host ----------------
extern "C" void kernel_launch(void* const* d_in, const int* in_sizes, int n_in,
                              void* d_out, int out_size, void* d_ws, size_t ws_size,
                              hipStream_t stream) {
  const float* x      = (const float*)d_in[0];
  const float* ln1_w  = (const float*)d_in[1];
  const float* ln1_b  = (const float*)d_in[2];
  const float* qkv_w  = (const float*)d_in[3];
  const float* qkv_b  = (const float*)d_in[4];
  const float* proj_w = (const float*)d_in[5];
  const float* proj_b = (const float*)d_in[6];
  const float* ln2_w  = (const float*)d_in[7];
  const float* ln2_b  = (const float*)d_in[8];
  const float* mlp_w1 = (const float*)d_in[9];
  const float* mlp_b1 = (const float*)d_in[10];
  const float* mlp_w2 = (const float*)d_in[11];
  const float* mlp_b2 = (const float*)d_in[12];
  float* out = (float*)d_out;

  char* ws = (char*)d_ws;
  const size_t MB = 1ull << 20;
  bf16* qkvT  = (bf16*)ws;
  bf16* projT = qkvT + 3 * 1024 * 1024;
  bf16* w1T   = qkvT + 4 * 1024 * 1024;
  bf16* w2T   = qkvT + 6 * 1024 * 1024;
  bf16* xn    = (bf16*)(ws + 16 * MB);
  bf16* qkvb  = (bf16*)(ws + 48 * MB);
  bf16* h1    = qkvb;
  bf16* Vt    = (bf16*)(ws + 144 * MB);

  int CH; bool useVt, x1f32;
  if      (ws_size >= 304 * MB) { CH = 16; useVt = true;  x1f32 = true;  }
  else if (ws_size >= 240 * MB) { CH = 8;  useVt = true;  x1f32 = true;  }
  else if (ws_size >= 208 * MB) { CH = 4;  useVt = true;  x1f32 = false; }
  else                          { CH = 4;  useVt = false; x1f32 = false; }
  char* R = ws + (useVt ? 176 * MB : 144 * MB);
  bf16*  scores = (bf16*)R;
  float* x1f    = (float*)R;   // overlays scores after attention
  bf16*  x1h    = (bf16*)R;

  ZOffs z0 = {};
  const float scale = 0.04419417382415922f;  // 1/sqrt(512)
  dim3 blk(256);

  // 0. weight transpose+convert
  hipLaunchKernelGGL(tconv_kernel, dim3(H3 / 32, C / 32), blk, 0, stream, qkv_w, qkvT, C, H3);
  hipLaunchKernelGGL(tconv_kernel, dim3(C / 32, C / 32), blk, 0, stream, proj_w, projT, C, C);
  hipLaunchKernelGGL(tconv_kernel, dim3(MH / 32, C / 32), blk, 0, stream, mlp_w1, w1T, C, MH);
  hipLaunchKernelGGL(tconv_kernel, dim3(C / 32, MH / 32), blk, 0, stream, mlp_w2, w2T, MH, C);

  // 1. LN1
  hipLaunchKernelGGL((ln_kernel<float>), dim3(MR), blk, 0, stream, x, ln1_w, ln1_b, xn);

  // 2. QKV = xn @ qkv_w + b -> bf16 [16384,3072]
  hipLaunchKernelGGL((gemm_k<F_TRANSB | F_BIAS | F_OUTBF16>),
                     dim3(H3 / TILE, MR / TILE, 1), blk, 0, stream,
                     xn, qkvT, (void*)qkvb, qkv_b, nullptr, C, C, C, H3, 1.0f, z0);

  // 2b. Vt
  if (useVt)
    hipLaunchKernelGGL(vtrans_kernel, dim3(SEQ / 32, DH / 32, 16), blk, 0, stream, qkvb, Vt);

  // 3. attention in chunks of CH (b,h) pairs
  for (int ch = 0; ch < 16 / CH; ch++) {
    ZOffs zq = {}, zp = {};
    for (int zz = 0; zz < CH; zz++) {
      int bh = ch * CH + zz, b = bh >> 1, hh = bh & 1;
      zq.a[zz] = (long long)b * SEQ * H3 + (long long)hh * DH;          // Q
      zq.b[zz] = (long long)b * SEQ * H3 + C + (long long)hh * DH;      // K
      zq.c[zz] = (long long)zz * SEQ * SEQ;                             // scores
      zp.a[zz] = (long long)zz * SEQ * SEQ;                             // probs
      zp.b[zz] = useVt ? (long long)bh * DH * SEQ                       // Vt slice
                       : (long long)b * SEQ * H3 + 2 * C + (long long)hh * DH;
      zp.c[zz] = (long long)b * SEQ * C + (long long)hh * DH;           // attn_out
    }
    hipLaunchKernelGGL((gemm_k<F_TRANSB | F_SCALE | F_OUTBF16>),
                       dim3(SEQ / TILE, SEQ / TILE, CH), blk, 0, stream,
                       qkvb, qkvb, (void*)scores, nullptr, nullptr, DH, H3, H3, SEQ, scale, zq);
    hipLaunchKernelGGL(softmax_kernel, dim3(SEQ, CH), blk, 0, stream, scores);
    if (useVt)
      hipLaunchKernelGGL((gemm_k<F_TRANSB | F_OUTBF16>),
                         dim3(DH / TILE, SEQ / TILE, CH), blk, 0, stream,
                         scores, Vt, (void*)xn, nullptr, nullptr, SEQ, SEQ, SEQ, C, 1.0f, zp);
    else
      hipLaunchKernelGGL((gemm_k<F_OUTBF16>),
                         dim3(DH / TILE, SEQ / TILE, CH), blk, 0, stream,
                         scores, qkvb, (void*)xn, nullptr, nullptr, SEQ, SEQ, H3, C, 1.0f, zp);
  }

  // 4. x1 = attn_out @ proj_w + b + x ; LN2 -> xn2
  if (x1f32) {
    hipLaunchKernelGGL((gemm_k<F_TRANSB | F_BIAS | F_RES | F_RESF32>),
                       dim3(C / TILE, MR / TILE, 1), blk, 0, stream,
                       xn, projT, (void*)x1f, proj_b, (const void*)x, C, C, C, C, 1.0f, z0);
    hipLaunchKernelGGL((ln_kernel<float>), dim3(MR), blk, 0, stream, x1f, ln2_w, ln2_b, xn);
  } else {
    hipLaunchKernelGGL((gemm_k<F_TRANSB | F_BIAS | F_RES | F_RESF32 | F_OUTBF16>),
                       dim3(C / TILE, MR / TILE, 1), blk, 0, stream,
                       xn, projT, (void*)x1h, proj_b, (const void*)x, C, C, C, C, 1.0f, z0);
    hipLaunchKernelGGL((ln_kernel<bf16>), dim3(MR), blk, 0, stream, x1h, ln2_w, ln2_b, xn);
  }

  // 5. h1 = gelu(xn2 @ w1 + b1) -> bf16 [16384,2048]
  hipLaunchKernelGGL((gemm_k<F_TRANSB | F_BIAS | F_GELU | F_OUTBF16>),
                     dim3(MH / TILE, MR / TILE, 1), blk, 0, stream,
                     xn, w1T, (void*)h1, mlp_b1, nullptr, C, C, C, MH, 1.0f, z0);

  // 6. out = x1 + h1 @ w2 + b2 -> fp32 d_out
  if (x1f32) {
    hipLaunchKernelGGL((gemm_k<F_TRANSB | F_BIAS | F_RES | F_RESF32>),
                       dim3(C / TILE, MR / TILE, 1), blk, 0, stream,
                       h1, w2T, (void*)out, mlp_b2, (const void*)x1f, MH, MH, MH, C, 1.0f, z0);
  } else {
    hipLaunchKernelGGL((gemm_k<F_TRANSB | F_BIAS | F_RES>),
                       dim3(C / TILE, MR / TILE, 1), blk, 0, stream,
                       h1, w2T, (void*)out, mlp_b2, (const void*)x1h, MH, MH, MH, C, 1.0f, z0);
  }
}